// Round 1
// baseline (219.563 us; speedup 1.0000x reference)
//
#include <hip/hip_runtime.h>
#include <hip/hip_bf16.h>

#define S_DIM 128
#define N_DIM 256
#define CIN   256
#define CH    32
#define COUT  128

typedef __attribute__((ext_vector_type(8))) short bf16x8;
typedef __attribute__((ext_vector_type(4))) float f32x4;
typedef __attribute__((ext_vector_type(16))) float f32x16;

__device__ __forceinline__ unsigned short f2bf(float f) {
  union { float f; unsigned int u; } v; v.f = f;
  unsigned int u = v.u;
  return (unsigned short)((u + 0x7FFFu + ((u >> 16) & 1u)) >> 16);
}

// packed f32x2 -> bf16x2 (RNE)
__device__ __forceinline__ unsigned int pk2(float x, float y) {
  float2 f2; f2.x = x; f2.y = y;
  __hip_bfloat162 h = __float22bfloat162_rn(f2);
  union { __hip_bfloat162 h; unsigned int u; } c; c.h = h;
  return c.u;
}

// ---------------------------------------------------------------------------
// Front-end (R4-verified, unchanged): merged LN+projection and prep.
//   blocks 0..1023   : LayerNorm + MFMA projection (wab in LDS)
//   blocks 1024..1151: wo3 = Wo bf16 packed for 32x32x16 B-frags
//   blocks 1152..1407: rnm = 1 / clip(mask^T mask, 1)
// ---------------------------------------------------------------------------
__global__ __launch_bounds__(256) void lnp_prep_kernel(
    const float* __restrict__ m, const float* __restrict__ mask,
    const float* __restrict__ gamma, const float* __restrict__ beta,
    const float* __restrict__ Wa, const float* __restrict__ Wb,
    const float* __restrict__ Wo,
    float* __restrict__ rnm, unsigned short* __restrict__ wo3,
    unsigned short* __restrict__ a_t, unsigned short* __restrict__ b_t) {
  const int b = blockIdx.x, t = threadIdx.x;
  if (b < 1024) {
    __shared__ __align__(16) unsigned short mn[32][264];   // +8 pad
    __shared__ __align__(16) unsigned short wabs[64 * 256];
    const int i = b & 255, s0 = (b >> 8) * 32;
    const int w = t >> 6, l = t & 63, lq = l >> 4, lr = l & 15;

    // Wa/Wb -> wabs, granule-swizzled: g' = (g&16)|((g ^ (r&15))&15)
    #pragma unroll
    for (int it = 0; it < 8; it++) {
      const int gi = it * 256 + t;       // granule 0..2047 (64 rows x 32)
      const int r = gi >> 5, g = gi & 31;
      const float* src = (r < 32) ? (Wa + r * 256 + g * 8)
                                  : (Wb + (r - 32) * 256 + g * 8);
      const int gp = (g & 16) | ((g ^ (r & 15)) & 15);
      unsigned short* dst = &wabs[r * 256 + gp * 8];
      const float4 v0 = *(const float4*)(src);
      const float4 v1 = *(const float4*)(src + 4);
      dst[0] = f2bf(v0.x); dst[1] = f2bf(v0.y); dst[2] = f2bf(v0.z); dst[3] = f2bf(v0.w);
      dst[4] = f2bf(v1.x); dst[5] = f2bf(v1.y); dst[6] = f2bf(v1.z); dst[7] = f2bf(v1.w);
    }

    const float4 g4 = *(const float4*)(gamma + l * 4);
    const float4 b4 = *(const float4*)(beta + l * 4);

    for (int rr = 0; rr < 8; rr++) {
      const int r = w * 8 + rr;
      const int s = s0 + r;
      const float4 v = *(const float4*)(m + ((size_t)(s * N_DIM + i)) * CIN + l * 4);
      float sum = v.x + v.y + v.z + v.w;
      float sq  = v.x * v.x + v.y * v.y + v.z * v.z + v.w * v.w;
      #pragma unroll
      for (int off = 32; off > 0; off >>= 1) {
        sum += __shfl_down(sum, off);
        sq  += __shfl_down(sq, off);
      }
      sum = __shfl(sum, 0); sq = __shfl(sq, 0);
      const float mu = sum * (1.0f / CIN);
      const float var = fmaxf(sq * (1.0f / CIN) - mu * mu, 0.0f);
      const float rs = rsqrtf(var + 1e-5f);
      const float mk = mask[s * N_DIM + i];
      ushort4 p;
      p.x = f2bf(((v.x - mu) * rs * g4.x + b4.x) * mk);
      p.y = f2bf(((v.y - mu) * rs * g4.y + b4.y) * mk);
      p.z = f2bf(((v.z - mu) * rs * g4.z + b4.z) * mk);
      p.w = f2bf(((v.w - mu) * rs * g4.w + b4.w) * mk);
      *(ushort4*)(&mn[r][l * 4]) = p;
    }
    __syncthreads();

    // MFMA: M=32 s-rows, N=64 [Wa|Wb], K=256
    const int wm = w & 1;
    const int n2 = w >> 1;
    f32x4 acc0 = {0.f, 0.f, 0.f, 0.f}, acc1 = {0.f, 0.f, 0.f, 0.f};
    #pragma unroll
    for (int ks = 0; ks < 8; ks++) {
      const int k0 = ks * 32 + lq * 8;
      const int g = ks * 4 + lq;
      const int gp = (g & 16) | ((g ^ lr) & 15);
      const bf16x8 af = *(const bf16x8*)(&mn[wm * 16 + lr][k0]);
      const bf16x8 bf0 = *(const bf16x8*)(&wabs[(n2 * 32 + lr) * 256 + gp * 8]);
      const bf16x8 bf1 = *(const bf16x8*)(&wabs[(n2 * 32 + 16 + lr) * 256 + gp * 8]);
      acc0 = __builtin_amdgcn_mfma_f32_16x16x32_bf16(af, bf0, acc0, 0, 0, 0);
      acc1 = __builtin_amdgcn_mfma_f32_16x16x32_bf16(af, bf1, acc1, 0, 0, 0);
    }

    unsigned short* dst = (n2 == 0) ? a_t : b_t;
    const int scol = s0 + wm * 16 + lq * 4;
    ushort4 q0, q1;
    q0.x = f2bf(acc0[0]); q0.y = f2bf(acc0[1]); q0.z = f2bf(acc0[2]); q0.w = f2bf(acc0[3]);
    q1.x = f2bf(acc1[0]); q1.y = f2bf(acc1[1]); q1.z = f2bf(acc1[2]); q1.w = f2bf(acc1[3]);
    *(ushort4*)(dst + ((size_t)(i * CH + lr)) * S_DIM + scol) = q0;
    *(ushort4*)(dst + ((size_t)(i * CH + 16 + lr)) * S_DIM + scol) = q1;
  } else if (b < 1152) {
    const int r = b - 1024;  // 0..127
    #pragma unroll
    for (int q = 0; q < 4; q++) {
      const int f = r * 1024 + q * 256 + t;        // 0..131071
      const int e = f & 7, l = (f >> 3) & 63;
      const int step = (f >> 9) & 63, og = f >> 15;
      const int kp = step * 16 + (l >> 5) * 8 + e;
      const int c = kp & 31, d = kp >> 5;
      const int o = og * 32 + (l & 31);
      wo3[f] = f2bf(Wo[o * 1024 + c * 32 + d]);
    }
  } else {
    const int i = b - 1152;  // 0..255
    float acc = 0.f;
    #pragma unroll 8
    for (int s = 0; s < S_DIM; s++)
      acc += mask[s * N_DIM + i] * mask[s * N_DIM + t];
    acc = fmaxf(acc, 1.0f);
    rnm[i * N_DIM + t] = 1.0f / acc;
  }
}

// ---------------------------------------------------------------------------
// fused v6: persistent blocks (256 x 4 tiles) with register prefetch of the
// next tile's a/b panels issued during the reduce/epilogue phase.
//   stage  : pf regs -> sA/sB, XOR-swizzled 16B granules (as before)
//   GEMM1  : 16 waves, 64x64 per wave, 16x16x32, K=128 (unchanged)
//   transp : acc -> sZ[pair][k'=d*32+c], b64 packed-cvt (unchanged)
//   GEMM2  : wave = (og = w&3: 32 o, kq = w>>2: K quarter). M=64: both
//            pair-halves share one wf read -> wo3 L2 traffic halved
//            (256 KB/block). 2 zf + 1 wf + 2 MFMA per k-step, 16 steps.
//   reduce : all 16 waves write kq-partials to fpart (128 KB, XOR-swizzled
//            conflict-free), then all 1024 threads sum 4 partials and emit
//            two coalesced float4 stores (one rnm load per thread).
// ---------------------------------------------------------------------------
__global__ __launch_bounds__(1024, 4) void fused_kernel(
    const unsigned short* __restrict__ a_t, const unsigned short* __restrict__ b_t,
    const unsigned short* __restrict__ wo3, const float* __restrict__ rnm,
    const float* __restrict__ bo, float* __restrict__ out) {
  extern __shared__ __align__(16) unsigned short smem[];
  unsigned short* sA = smem;            // 256 x 128 = 64 KB
  unsigned short* sB = smem + 32768;    // 256 x 128 = 64 KB
  unsigned short* sZ = smem;            // 64 pairs x 1024 = 128 KB overlay
  float* fpart = (float*)smem;          // 4 kq x 8192 f32 = 128 KB overlay

  const int t = threadIdx.x, w = t >> 6, l = t & 63;
  const int lq = l >> 4, lr = l & 15;

  // loop-invariant epilogue mapping: thread -> (pair, 8 consecutive o)
  const int pair = t >> 4;              // 0..63
  const int ob   = (t & 15) * 8;        // 0..120
  const float4 bo0 = *(const float4*)(bo + ob);
  const float4 bo1 = *(const float4*)(bo + ob + 4);
  const int opc = pair * 128 + (ob ^ ((pair & 3) << 3));

  // GEMM2 wave job (loop-invariant)
  const int og = w & 3, kq = w >> 2;    // og: o-group, kq: K quarter
  const int pA = l & 31, pB = 32 + pA;
  const unsigned short* wop =
      wo3 + ((size_t)(og * 64 + kq * 16) * 64 + l) * 8;
  const int oc = og * 32 + (l & 31);

  int tt = blockIdx.x;                  // tile id; +256 per round

  // prefetch tile 0 into regs
  bf16x8 pfA[4], pfB[4];
  {
    const unsigned short* srcA = a_t + (size_t)(tt >> 5) * 32768;
    const unsigned short* srcB = b_t + (size_t)(tt & 31) * 32768;
    #pragma unroll
    for (int it = 0; it < 4; it++) {
      pfA[it] = *(const bf16x8*)(srcA + (it * 1024 + t) * 8);
      pfB[it] = *(const bf16x8*)(srcB + (it * 1024 + t) * 8);
    }
  }

  #pragma unroll 1
  for (int rep = 0; rep < 4; ++rep) {
    const int bx = tt >> 5, by = tt & 31;

    // ---- stage: regs -> LDS, swizzle g' = g ^ (r&15) ----
    #pragma unroll
    for (int it = 0; it < 4; it++) {
      const int idx = it * 1024 + t;       // granule 0..4095
      const int rw = idx >> 4, g = idx & 15;
      const int dst = rw * 128 + ((g ^ (rw & 15)) * 8);
      *(bf16x8*)(&sA[dst]) = pfA[it];
      *(bf16x8*)(&sB[dst]) = pfB[it];
    }
    __syncthreads();

    // ---- GEMM1: K=128 = 4 MFMA k-steps. Wave (wy,wx) owns 64x64. ----
    const int wy = (w >> 2) * 64, wx = (w & 3) * 64;
    f32x4 acc[4][4];
    #pragma unroll
    for (int a2 = 0; a2 < 4; a2++)
      #pragma unroll
      for (int c2 = 0; c2 < 4; c2++) acc[a2][c2] = (f32x4){0.f, 0.f, 0.f, 0.f};

    #pragma unroll
    for (int ks = 0; ks < 4; ks++) {
      const int g0 = ks * 4 + lq;
      bf16x8 afr[4], bfr[4];
      #pragma unroll
      for (int a2 = 0; a2 < 4; a2++) {
        const int ra = wy + a2 * 16 + lr;
        afr[a2] = *(const bf16x8*)(&sA[ra * 128 + ((g0 ^ (ra & 15)) * 8)]);
        const int rb = wx + a2 * 16 + lr;
        bfr[a2] = *(const bf16x8*)(&sB[rb * 128 + ((g0 ^ (rb & 15)) * 8)]);
      }
      #pragma unroll
      for (int a2 = 0; a2 < 4; a2++)
        #pragma unroll
        for (int c2 = 0; c2 < 4; c2++)
          acc[a2][c2] = __builtin_amdgcn_mfma_f32_16x16x32_bf16(afr[a2], bfr[c2], acc[a2][c2], 0, 0, 0);
    }
    __syncthreads();  // all GEMM1 reads done before sZ overlays sA/sB

    // ---- transpose: acc (C/D layout) -> sZ[pair][k'=d*32+c] ----
    // Granule map: gp = (g&~7) | ((g ^ (g>>3) ^ pair) & 7)
    #pragma unroll
    for (int a2 = 0; a2 < 4; a2++) {
      #pragma unroll
      for (int c2 = 0; c2 < 4; c2++) {
        const int zrb = wy + a2 * 16 + lq * 4;
        const int zc  = wx + c2 * 16 + lr;
        const int pr = (zrb >> 5) * 8 + (zc >> 5);
        const int off = (zc & 31) * 32 + (zrb & 31);
        const int g = off >> 3;
        const int gp = (g & ~7) | ((g ^ (g >> 3) ^ pr) & 7);
        uint2 q;
        q.x = pk2(acc[a2][c2][0], acc[a2][c2][1]);
        q.y = pk2(acc[a2][c2][2], acc[a2][c2][3]);
        *(uint2*)(&sZ[pr * 1024 + gp * 8 + (off & 7)]) = q;
      }
    }
    __syncthreads();

    // ---- GEMM2: 32x32x16, M=64 (pairs 0-31 and 32-63 share each wf) ----
    f32x16 accA, accB;
    #pragma unroll
    for (int q2 = 0; q2 < 16; q2++) { accA[q2] = 0.f; accB[q2] = 0.f; }

    #pragma unroll 8
    for (int j = 0; j < 16; j++) {
      const int s = kq * 16 + j;                 // k-step (16 k each)
      const int g = s * 2 + (l >> 5);
      const int gA = (g & ~7) | ((g ^ (g >> 3) ^ pA) & 7);
      const int gB = (g & ~7) | ((g ^ (g >> 3) ^ pB) & 7);
      const bf16x8 zfA = *(const bf16x8*)(&sZ[pA * 1024 + gA * 8]);
      const bf16x8 zfB = *(const bf16x8*)(&sZ[pB * 1024 + gB * 8]);
      const bf16x8 wf = *(const bf16x8*)(wop + (size_t)j * 512);
      accA = __builtin_amdgcn_mfma_f32_32x32x16_bf16(zfA, wf, accA, 0, 0, 0);
      accB = __builtin_amdgcn_mfma_f32_32x32x16_bf16(zfB, wf, accB, 0, 0, 0);
    }
    __syncthreads();   // all z reads done; sZ region now free for partials

    // ---- kq-partials -> fpart, conflict-free via o ^ ((pair&3)<<3) ----
    #pragma unroll
    for (int q2 = 0; q2 < 16; q2++) {
      const int row = (q2 & 3) + 8 * (q2 >> 2) + 4 * (l >> 5);
      const int xo = oc ^ ((q2 & 3) << 3);       // (pair&3) == (q2&3)
      fpart[kq * 8192 + row * 128 + xo] = accA[q2];
      fpart[kq * 8192 + (row + 32) * 128 + xo] = accB[q2];
    }
    __syncthreads();

    // ---- epilogue: rnm load first, then next-tile prefetch, then reduce ----
    const int ii = bx * 8 + (pair >> 3), jj = by * 8 + (pair & 7);
    const float sc = rnm[ii * N_DIM + jj];

    if (rep < 3) {
      const int ntt = tt + 256;
      const unsigned short* srcA = a_t + (size_t)(ntt >> 5) * 32768;
      const unsigned short* srcB = b_t + (size_t)(ntt & 31) * 32768;
      #pragma unroll
      for (int it = 0; it < 4; it++) {
        pfA[it] = *(const bf16x8*)(srcA + (it * 1024 + t) * 8);
        pfB[it] = *(const bf16x8*)(srcB + (it * 1024 + t) * 8);
      }
    }

    f32x4 u0 = {0.f, 0.f, 0.f, 0.f}, u1 = {0.f, 0.f, 0.f, 0.f};
    #pragma unroll
    for (int q2 = 0; q2 < 4; q2++) {
      u0 += *(const f32x4*)(&fpart[q2 * 8192 + opc]);
      u1 += *(const f32x4*)(&fpart[q2 * 8192 + opc + 4]);
    }
    float* po = out + ((size_t)(ii * N_DIM + jj)) * COUT + ob;
    float4 w0, w1;
    w0.x = u0[0] * sc + bo0.x; w0.y = u0[1] * sc + bo0.y;
    w0.z = u0[2] * sc + bo0.z; w0.w = u0[3] * sc + bo0.w;
    w1.x = u1[0] * sc + bo1.x; w1.y = u1[1] * sc + bo1.y;
    w1.z = u1[2] * sc + bo1.z; w1.w = u1[3] * sc + bo1.w;
    *(float4*)(po)     = w0;
    *(float4*)(po + 4) = w1;
    __syncthreads();   // fpart reads done before next stage ds_write

    tt += 256;
  }
}

// ---------------------------------------------------------------------------
extern "C" void kernel_launch(void* const* d_in, const int* in_sizes, int n_in,
                              void* d_out, int out_size, void* d_ws, size_t ws_size,
                              hipStream_t stream) {
  const float* m     = (const float*)d_in[0];
  const float* mask  = (const float*)d_in[1];
  const float* gamma = (const float*)d_in[2];
  const float* beta  = (const float*)d_in[3];
  const float* Wa    = (const float*)d_in[4];
  const float* Wb    = (const float*)d_in[5];
  const float* Wo    = (const float*)d_in[6];
  const float* bo    = (const float*)d_in[7];
  float* out = (float*)d_out;

  char* ws = (char*)d_ws;
  float*          rnm = (float*)(ws);                     // 256 KB
  unsigned short* wo3 = (unsigned short*)(ws + 262144);   // 256 KB
  unsigned short* a_t = (unsigned short*)(ws + 524288);   //   2 MB
  unsigned short* b_t = (unsigned short*)(ws + 2621440);  //   2 MB

  hipFuncSetAttribute((const void*)fused_kernel,
                      hipFuncAttributeMaxDynamicSharedMemorySize, 131072);

  lnp_prep_kernel<<<1408, 256, 0, stream>>>(m, mask, gamma, beta, Wa, Wb, Wo,
                                            rnm, wo3, a_t, b_t);
  fused_kernel<<<256, 1024, 131072, stream>>>(a_t, b_t, wo3, rnm, bo, out);
}

// Round 2
// 151.730 us; speedup vs baseline: 1.4471x; 1.4471x over previous
//
#include <hip/hip_runtime.h>
#include <hip/hip_bf16.h>

#define S_DIM 128
#define N_DIM 256
#define CIN   256
#define CH    32
#define COUT  128

typedef __attribute__((ext_vector_type(8))) short bf16x8;
typedef __attribute__((ext_vector_type(4))) float f32x4;
typedef __attribute__((ext_vector_type(16))) float f32x16;

__device__ __forceinline__ unsigned short f2bf(float f) {
  union { float f; unsigned int u; } v; v.f = f;
  unsigned int u = v.u;
  return (unsigned short)((u + 0x7FFFu + ((u >> 16) & 1u)) >> 16);
}

// packed f32x2 -> bf16x2 (RNE)
__device__ __forceinline__ unsigned int pk2(float x, float y) {
  float2 f2; f2.x = x; f2.y = y;
  __hip_bfloat162 h = __float22bfloat162_rn(f2);
  union { __hip_bfloat162 h; unsigned int u; } c; c.h = h;
  return c.u;
}

// ---------------------------------------------------------------------------
// Front-end (R4-verified, unchanged): merged LN+projection and prep.
//   blocks 0..1023   : LayerNorm + MFMA projection (wab in LDS)
//   blocks 1024..1151: wo3 = Wo bf16 packed for 32x32x16 B-frags
//   blocks 1152..1407: rnm = 1 / clip(mask^T mask, 1)
// ---------------------------------------------------------------------------
__global__ __launch_bounds__(256) void lnp_prep_kernel(
    const float* __restrict__ m, const float* __restrict__ mask,
    const float* __restrict__ gamma, const float* __restrict__ beta,
    const float* __restrict__ Wa, const float* __restrict__ Wb,
    const float* __restrict__ Wo,
    float* __restrict__ rnm, unsigned short* __restrict__ wo3,
    unsigned short* __restrict__ a_t, unsigned short* __restrict__ b_t) {
  const int b = blockIdx.x, t = threadIdx.x;
  if (b < 1024) {
    __shared__ __align__(16) unsigned short mn[32][264];   // +8 pad
    __shared__ __align__(16) unsigned short wabs[64 * 256];
    const int i = b & 255, s0 = (b >> 8) * 32;
    const int w = t >> 6, l = t & 63, lq = l >> 4, lr = l & 15;

    // Wa/Wb -> wabs, granule-swizzled: g' = (g&16)|((g ^ (r&15))&15)
    #pragma unroll
    for (int it = 0; it < 8; it++) {
      const int gi = it * 256 + t;       // granule 0..2047 (64 rows x 32)
      const int r = gi >> 5, g = gi & 31;
      const float* src = (r < 32) ? (Wa + r * 256 + g * 8)
                                  : (Wb + (r - 32) * 256 + g * 8);
      const int gp = (g & 16) | ((g ^ (r & 15)) & 15);
      unsigned short* dst = &wabs[r * 256 + gp * 8];
      const float4 v0 = *(const float4*)(src);
      const float4 v1 = *(const float4*)(src + 4);
      dst[0] = f2bf(v0.x); dst[1] = f2bf(v0.y); dst[2] = f2bf(v0.z); dst[3] = f2bf(v0.w);
      dst[4] = f2bf(v1.x); dst[5] = f2bf(v1.y); dst[6] = f2bf(v1.z); dst[7] = f2bf(v1.w);
    }

    const float4 g4 = *(const float4*)(gamma + l * 4);
    const float4 b4 = *(const float4*)(beta + l * 4);

    for (int rr = 0; rr < 8; rr++) {
      const int r = w * 8 + rr;
      const int s = s0 + r;
      const float4 v = *(const float4*)(m + ((size_t)(s * N_DIM + i)) * CIN + l * 4);
      float sum = v.x + v.y + v.z + v.w;
      float sq  = v.x * v.x + v.y * v.y + v.z * v.z + v.w * v.w;
      #pragma unroll
      for (int off = 32; off > 0; off >>= 1) {
        sum += __shfl_down(sum, off);
        sq  += __shfl_down(sq, off);
      }
      sum = __shfl(sum, 0); sq = __shfl(sq, 0);
      const float mu = sum * (1.0f / CIN);
      const float var = fmaxf(sq * (1.0f / CIN) - mu * mu, 0.0f);
      const float rs = rsqrtf(var + 1e-5f);
      const float mk = mask[s * N_DIM + i];
      ushort4 p;
      p.x = f2bf(((v.x - mu) * rs * g4.x + b4.x) * mk);
      p.y = f2bf(((v.y - mu) * rs * g4.y + b4.y) * mk);
      p.z = f2bf(((v.z - mu) * rs * g4.z + b4.z) * mk);
      p.w = f2bf(((v.w - mu) * rs * g4.w + b4.w) * mk);
      *(ushort4*)(&mn[r][l * 4]) = p;
    }
    __syncthreads();

    // MFMA: M=32 s-rows, N=64 [Wa|Wb], K=256
    const int wm = w & 1;
    const int n2 = w >> 1;
    f32x4 acc0 = {0.f, 0.f, 0.f, 0.f}, acc1 = {0.f, 0.f, 0.f, 0.f};
    #pragma unroll
    for (int ks = 0; ks < 8; ks++) {
      const int k0 = ks * 32 + lq * 8;
      const int g = ks * 4 + lq;
      const int gp = (g & 16) | ((g ^ lr) & 15);
      const bf16x8 af = *(const bf16x8*)(&mn[wm * 16 + lr][k0]);
      const bf16x8 bf0 = *(const bf16x8*)(&wabs[(n2 * 32 + lr) * 256 + gp * 8]);
      const bf16x8 bf1 = *(const bf16x8*)(&wabs[(n2 * 32 + 16 + lr) * 256 + gp * 8]);
      acc0 = __builtin_amdgcn_mfma_f32_16x16x32_bf16(af, bf0, acc0, 0, 0, 0);
      acc1 = __builtin_amdgcn_mfma_f32_16x16x32_bf16(af, bf1, acc1, 0, 0, 0);
    }

    unsigned short* dst = (n2 == 0) ? a_t : b_t;
    const int scol = s0 + wm * 16 + lq * 4;
    ushort4 q0, q1;
    q0.x = f2bf(acc0[0]); q0.y = f2bf(acc0[1]); q0.z = f2bf(acc0[2]); q0.w = f2bf(acc0[3]);
    q1.x = f2bf(acc1[0]); q1.y = f2bf(acc1[1]); q1.z = f2bf(acc1[2]); q1.w = f2bf(acc1[3]);
    *(ushort4*)(dst + ((size_t)(i * CH + lr)) * S_DIM + scol) = q0;
    *(ushort4*)(dst + ((size_t)(i * CH + 16 + lr)) * S_DIM + scol) = q1;
  } else if (b < 1152) {
    const int r = b - 1024;  // 0..127
    #pragma unroll
    for (int q = 0; q < 4; q++) {
      const int f = r * 1024 + q * 256 + t;        // 0..131071
      const int e = f & 7, l = (f >> 3) & 63;
      const int step = (f >> 9) & 63, og = f >> 15;
      const int kp = step * 16 + (l >> 5) * 8 + e;
      const int c = kp & 31, d = kp >> 5;
      const int o = og * 32 + (l & 31);
      wo3[f] = f2bf(Wo[o * 1024 + c * 32 + d]);
    }
  } else {
    const int i = b - 1152;  // 0..255
    float acc = 0.f;
    #pragma unroll 8
    for (int s = 0; s < S_DIM; s++)
      acc += mask[s * N_DIM + i] * mask[s * N_DIM + t];
    acc = fmaxf(acc, 1.0f);
    rnm[i * N_DIM + t] = 1.0f / acc;
  }
}

// ---------------------------------------------------------------------------
// fused v7: v5 structure (1024 blocks, no persistence — R1 showed the
// cross-phase prefetch registers spill to scratch: +340 MB HBM round-trip)
// with the two R1-verified improvements kept:
//   GEMM2  : wave = (og = w&3: 32 o, kq = w>>2: K quarter). M=64: both
//            pair-halves share one wf read -> wo3 L2 traffic halved
//            (256 KB/block, the floor — wo3 must be read once per tile).
//   reduce : all 16 waves write kq-partials to fpart (128 KB, XOR-swizzled
//            conflict-free), then all 1024 threads sum 4 partials and emit
//            two coalesced float4 stores (one rnm load per thread).
// ---------------------------------------------------------------------------
__global__ __launch_bounds__(1024, 4) void fused_kernel(
    const unsigned short* __restrict__ a_t, const unsigned short* __restrict__ b_t,
    const unsigned short* __restrict__ wo3, const float* __restrict__ rnm,
    const float* __restrict__ bo, float* __restrict__ out) {
  extern __shared__ __align__(16) unsigned short smem[];
  unsigned short* sA = smem;            // 256 x 128 = 64 KB
  unsigned short* sB = smem + 32768;    // 256 x 128 = 64 KB
  unsigned short* sZ = smem;            // 64 pairs x 1024 = 128 KB overlay
  float* fpart = (float*)smem;          // 4 kq x 8192 f32 = 128 KB overlay

  const int t = threadIdx.x, w = t >> 6, l = t & 63;
  const int lq = l >> 4, lr = l & 15;
  const int bx = blockIdx.x, by = blockIdx.y;

  // Stage: 4096 granules/tile; swizzle g' = g ^ (r&15)
  const unsigned short* srcA = a_t + (size_t)bx * 32768;
  const unsigned short* srcB = b_t + (size_t)by * 32768;
  #pragma unroll
  for (int it = 0; it < 4; it++) {
    const int idx = it * 1024 + t;       // granule 0..4095
    const int r = idx >> 4, g = idx & 15;
    const int dst = r * 128 + ((g ^ (r & 15)) * 8);
    *(bf16x8*)(&sA[dst]) = *(const bf16x8*)(srcA + idx * 8);
    *(bf16x8*)(&sB[dst]) = *(const bf16x8*)(srcB + idx * 8);
  }
  __syncthreads();

  // GEMM1: K=128 = 4 MFMA k-steps. Wave (wy,wx) owns 64x64.
  const int wy = (w >> 2) * 64, wx = (w & 3) * 64;
  f32x4 acc[4][4];
  #pragma unroll
  for (int a = 0; a < 4; a++)
    #pragma unroll
    for (int c = 0; c < 4; c++) acc[a][c] = (f32x4){0.f, 0.f, 0.f, 0.f};

  #pragma unroll
  for (int ks = 0; ks < 4; ks++) {
    const int g0 = ks * 4 + lq;
    bf16x8 afr[4], bfr[4];
    #pragma unroll
    for (int a = 0; a < 4; a++) {
      const int ra = wy + a * 16 + lr;
      afr[a] = *(const bf16x8*)(&sA[ra * 128 + ((g0 ^ (ra & 15)) * 8)]);
      const int rb = wx + a * 16 + lr;
      bfr[a] = *(const bf16x8*)(&sB[rb * 128 + ((g0 ^ (rb & 15)) * 8)]);
    }
    #pragma unroll
    for (int a = 0; a < 4; a++)
      #pragma unroll
      for (int c = 0; c < 4; c++)
        acc[a][c] = __builtin_amdgcn_mfma_f32_16x16x32_bf16(afr[a], bfr[c], acc[a][c], 0, 0, 0);
  }
  __syncthreads();  // all GEMM1 reads done before sZ overlays sA/sB

  // Transpose: acc (C/D layout) -> sZ[pair][k'=d*32+c], b64 packed-cvt writes.
  // Granule map: gp = (g&~7) | ((g ^ (g>>3) ^ pair) & 7)
  #pragma unroll
  for (int a = 0; a < 4; a++) {
    #pragma unroll
    for (int c = 0; c < 4; c++) {
      const int zrb = wy + a * 16 + lq * 4;
      const int zc  = wx + c * 16 + lr;
      const int pr = (zrb >> 5) * 8 + (zc >> 5);
      const int off = (zc & 31) * 32 + (zrb & 31);
      const int g = off >> 3;
      const int gp = (g & ~7) | ((g ^ (g >> 3) ^ pr) & 7);
      uint2 q;
      q.x = pk2(acc[a][c][0], acc[a][c][1]);
      q.y = pk2(acc[a][c][2], acc[a][c][3]);
      *(uint2*)(&sZ[pr * 1024 + gp * 8 + (off & 7)]) = q;
    }
  }
  __syncthreads();

  // GEMM2: 32x32x16, M=64 (pairs 0-31 and 32-63 share each wf fragment).
  // A-frag: m = pair, k = (l>>5)*8+j. B-frag: n = o = og*32+(l&31).
  const int og = w & 3, kq = w >> 2;    // og: o-group, kq: K quarter
  const int pA = l & 31, pB = 32 + pA;
  const unsigned short* wop =
      wo3 + ((size_t)(og * 64 + kq * 16) * 64 + l) * 8;
  f32x16 accA, accB;
  #pragma unroll
  for (int r = 0; r < 16; r++) { accA[r] = 0.f; accB[r] = 0.f; }

  #pragma unroll 8
  for (int j = 0; j < 16; j++) {
    const int s = kq * 16 + j;                 // k-step (16 k each)
    const int g = s * 2 + (l >> 5);            // granule of this lane's chunk
    const int gA = (g & ~7) | ((g ^ (g >> 3) ^ pA) & 7);
    const int gB = (g & ~7) | ((g ^ (g >> 3) ^ pB) & 7);
    const bf16x8 zfA = *(const bf16x8*)(&sZ[pA * 1024 + gA * 8]);
    const bf16x8 zfB = *(const bf16x8*)(&sZ[pB * 1024 + gB * 8]);
    const bf16x8 wf = *(const bf16x8*)(wop + (size_t)j * 512);
    accA = __builtin_amdgcn_mfma_f32_32x32x16_bf16(zfA, wf, accA, 0, 0, 0);
    accB = __builtin_amdgcn_mfma_f32_32x32x16_bf16(zfB, wf, accB, 0, 0, 0);
  }
  __syncthreads();   // all z reads done; sZ region now free for partials

  // kq-partials -> fpart, conflict-free via o ^ ((pair&3)<<3)
  const int oc = og * 32 + (l & 31);
  #pragma unroll
  for (int r = 0; r < 16; r++) {
    const int row = (r & 3) + 8 * (r >> 2) + 4 * (l >> 5);   // pair row 0..31
    const int xo = oc ^ ((r & 3) << 3);        // (row&3) == (r&3)
    fpart[kq * 8192 + row * 128 + xo] = accA[r];
    fpart[kq * 8192 + (row + 32) * 128 + xo] = accB[r];
  }
  __syncthreads();

  // Epilogue: all 1024 threads; thread -> (pair = t>>4, 8 consecutive o).
  const int pair = t >> 4;              // 0..63
  const int ob   = (t & 15) * 8;        // 0..120
  const float4 bo0 = *(const float4*)(bo + ob);
  const float4 bo1 = *(const float4*)(bo + ob + 4);
  const int opc = pair * 128 + (ob ^ ((pair & 3) << 3));

  const int ii = bx * 8 + (pair >> 3), jj = by * 8 + (pair & 7);
  const float sc = rnm[ii * N_DIM + jj];

  f32x4 u0 = {0.f, 0.f, 0.f, 0.f}, u1 = {0.f, 0.f, 0.f, 0.f};
  #pragma unroll
  for (int q = 0; q < 4; q++) {
    u0 += *(const f32x4*)(&fpart[q * 8192 + opc]);
    u1 += *(const f32x4*)(&fpart[q * 8192 + opc + 4]);
  }
  float* po = out + ((size_t)(ii * N_DIM + jj)) * COUT + ob;
  float4 w0, w1;
  w0.x = u0[0] * sc + bo0.x; w0.y = u0[1] * sc + bo0.y;
  w0.z = u0[2] * sc + bo0.z; w0.w = u0[3] * sc + bo0.w;
  w1.x = u1[0] * sc + bo1.x; w1.y = u1[1] * sc + bo1.y;
  w1.z = u1[2] * sc + bo1.z; w1.w = u1[3] * sc + bo1.w;
  *(float4*)(po)     = w0;
  *(float4*)(po + 4) = w1;
}

// ---------------------------------------------------------------------------
extern "C" void kernel_launch(void* const* d_in, const int* in_sizes, int n_in,
                              void* d_out, int out_size, void* d_ws, size_t ws_size,
                              hipStream_t stream) {
  const float* m     = (const float*)d_in[0];
  const float* mask  = (const float*)d_in[1];
  const float* gamma = (const float*)d_in[2];
  const float* beta  = (const float*)d_in[3];
  const float* Wa    = (const float*)d_in[4];
  const float* Wb    = (const float*)d_in[5];
  const float* Wo    = (const float*)d_in[6];
  const float* bo    = (const float*)d_in[7];
  float* out = (float*)d_out;

  char* ws = (char*)d_ws;
  float*          rnm = (float*)(ws);                     // 256 KB
  unsigned short* wo3 = (unsigned short*)(ws + 262144);   // 256 KB
  unsigned short* a_t = (unsigned short*)(ws + 524288);   //   2 MB
  unsigned short* b_t = (unsigned short*)(ws + 2621440);  //   2 MB

  hipFuncSetAttribute((const void*)fused_kernel,
                      hipFuncAttributeMaxDynamicSharedMemorySize, 131072);

  lnp_prep_kernel<<<1408, 256, 0, stream>>>(m, mask, gamma, beta, Wa, Wb, Wo,
                                            rnm, wo3, a_t, b_t);
  fused_kernel<<<dim3(32, 32), 1024, 131072, stream>>>(a_t, b_t, wo3, rnm, bo, out);
}

// Round 3
// 147.023 us; speedup vs baseline: 1.4934x; 1.0320x over previous
//
#include <hip/hip_runtime.h>
#include <hip/hip_bf16.h>

#define S_DIM 128
#define N_DIM 256
#define CIN   256
#define CH    32
#define COUT  128

typedef __attribute__((ext_vector_type(8))) short bf16x8;
typedef __attribute__((ext_vector_type(4))) float f32x4;
typedef __attribute__((ext_vector_type(16))) float f32x16;

__device__ __forceinline__ unsigned short f2bf(float f) {
  union { float f; unsigned int u; } v; v.f = f;
  unsigned int u = v.u;
  return (unsigned short)((u + 0x7FFFu + ((u >> 16) & 1u)) >> 16);
}

// packed f32x2 -> bf16x2 (RNE)
__device__ __forceinline__ unsigned int pk2(float x, float y) {
  float2 f2; f2.x = x; f2.y = y;
  __hip_bfloat162 h = __float22bfloat162_rn(f2);
  union { __hip_bfloat162 h; unsigned int u; } c; c.h = h;
  return c.u;
}

// ---------------------------------------------------------------------------
// Front-end (R4-verified, unchanged): merged LN+projection and prep.
//   blocks 0..1023   : LayerNorm + MFMA projection (wab in LDS)
//   blocks 1024..1151: wo3 = Wo bf16 packed for 32x32x16 B-frags
//   blocks 1152..1407: rnm = 1 / clip(mask^T mask, 1)
// ---------------------------------------------------------------------------
__global__ __launch_bounds__(256) void lnp_prep_kernel(
    const float* __restrict__ m, const float* __restrict__ mask,
    const float* __restrict__ gamma, const float* __restrict__ beta,
    const float* __restrict__ Wa, const float* __restrict__ Wb,
    const float* __restrict__ Wo,
    float* __restrict__ rnm, unsigned short* __restrict__ wo3,
    unsigned short* __restrict__ a_t, unsigned short* __restrict__ b_t) {
  const int b = blockIdx.x, t = threadIdx.x;
  if (b < 1024) {
    __shared__ __align__(16) unsigned short mn[32][264];   // +8 pad
    __shared__ __align__(16) unsigned short wabs[64 * 256];
    const int i = b & 255, s0 = (b >> 8) * 32;
    const int w = t >> 6, l = t & 63, lq = l >> 4, lr = l & 15;

    // Wa/Wb -> wabs, granule-swizzled: g' = (g&16)|((g ^ (r&15))&15)
    #pragma unroll
    for (int it = 0; it < 8; it++) {
      const int gi = it * 256 + t;       // granule 0..2047 (64 rows x 32)
      const int r = gi >> 5, g = gi & 31;
      const float* src = (r < 32) ? (Wa + r * 256 + g * 8)
                                  : (Wb + (r - 32) * 256 + g * 8);
      const int gp = (g & 16) | ((g ^ (r & 15)) & 15);
      unsigned short* dst = &wabs[r * 256 + gp * 8];
      const float4 v0 = *(const float4*)(src);
      const float4 v1 = *(const float4*)(src + 4);
      dst[0] = f2bf(v0.x); dst[1] = f2bf(v0.y); dst[2] = f2bf(v0.z); dst[3] = f2bf(v0.w);
      dst[4] = f2bf(v1.x); dst[5] = f2bf(v1.y); dst[6] = f2bf(v1.z); dst[7] = f2bf(v1.w);
    }

    const float4 g4 = *(const float4*)(gamma + l * 4);
    const float4 b4 = *(const float4*)(beta + l * 4);

    for (int rr = 0; rr < 8; rr++) {
      const int r = w * 8 + rr;
      const int s = s0 + r;
      const float4 v = *(const float4*)(m + ((size_t)(s * N_DIM + i)) * CIN + l * 4);
      float sum = v.x + v.y + v.z + v.w;
      float sq  = v.x * v.x + v.y * v.y + v.z * v.z + v.w * v.w;
      #pragma unroll
      for (int off = 32; off > 0; off >>= 1) {
        sum += __shfl_down(sum, off);
        sq  += __shfl_down(sq, off);
      }
      sum = __shfl(sum, 0); sq = __shfl(sq, 0);
      const float mu = sum * (1.0f / CIN);
      const float var = fmaxf(sq * (1.0f / CIN) - mu * mu, 0.0f);
      const float rs = rsqrtf(var + 1e-5f);
      const float mk = mask[s * N_DIM + i];
      ushort4 p;
      p.x = f2bf(((v.x - mu) * rs * g4.x + b4.x) * mk);
      p.y = f2bf(((v.y - mu) * rs * g4.y + b4.y) * mk);
      p.z = f2bf(((v.z - mu) * rs * g4.z + b4.z) * mk);
      p.w = f2bf(((v.w - mu) * rs * g4.w + b4.w) * mk);
      *(ushort4*)(&mn[r][l * 4]) = p;
    }
    __syncthreads();

    // MFMA: M=32 s-rows, N=64 [Wa|Wb], K=256
    const int wm = w & 1;
    const int n2 = w >> 1;
    f32x4 acc0 = {0.f, 0.f, 0.f, 0.f}, acc1 = {0.f, 0.f, 0.f, 0.f};
    #pragma unroll
    for (int ks = 0; ks < 8; ks++) {
      const int k0 = ks * 32 + lq * 8;
      const int g = ks * 4 + lq;
      const int gp = (g & 16) | ((g ^ lr) & 15);
      const bf16x8 af = *(const bf16x8*)(&mn[wm * 16 + lr][k0]);
      const bf16x8 bf0 = *(const bf16x8*)(&wabs[(n2 * 32 + lr) * 256 + gp * 8]);
      const bf16x8 bf1 = *(const bf16x8*)(&wabs[(n2 * 32 + 16 + lr) * 256 + gp * 8]);
      acc0 = __builtin_amdgcn_mfma_f32_16x16x32_bf16(af, bf0, acc0, 0, 0, 0);
      acc1 = __builtin_amdgcn_mfma_f32_16x16x32_bf16(af, bf1, acc1, 0, 0, 0);
    }

    unsigned short* dst = (n2 == 0) ? a_t : b_t;
    const int scol = s0 + wm * 16 + lq * 4;
    ushort4 q0, q1;
    q0.x = f2bf(acc0[0]); q0.y = f2bf(acc0[1]); q0.z = f2bf(acc0[2]); q0.w = f2bf(acc0[3]);
    q1.x = f2bf(acc1[0]); q1.y = f2bf(acc1[1]); q1.z = f2bf(acc1[2]); q1.w = f2bf(acc1[3]);
    *(ushort4*)(dst + ((size_t)(i * CH + lr)) * S_DIM + scol) = q0;
    *(ushort4*)(dst + ((size_t)(i * CH + 16 + lr)) * S_DIM + scol) = q1;
  } else if (b < 1152) {
    const int r = b - 1024;  // 0..127
    #pragma unroll
    for (int q = 0; q < 4; q++) {
      const int f = r * 1024 + q * 256 + t;        // 0..131071
      const int e = f & 7, l = (f >> 3) & 63;
      const int step = (f >> 9) & 63, og = f >> 15;
      const int kp = step * 16 + (l >> 5) * 8 + e;
      const int c = kp & 31, d = kp >> 5;
      const int o = og * 32 + (l & 31);
      wo3[f] = f2bf(Wo[o * 1024 + c * 32 + d]);
    }
  } else {
    const int i = b - 1152;  // 0..255
    float acc = 0.f;
    #pragma unroll 8
    for (int s = 0; s < S_DIM; s++)
      acc += mask[s * N_DIM + i] * mask[s * N_DIM + t];
    acc = fmaxf(acc, 1.0f);
    rnm[i * N_DIM + t] = 1.0f / acc;
  }
}

// ---------------------------------------------------------------------------
// fused v8: 2 blocks/CU for phase overlap. 256x128 z-tile (32 pairs),
// 8 waves (512 thr), 64 KB dynamic LDS, __launch_bounds__(512,4) -> 128 regs.
//   stage  : two K-chunks (sA 256x64 + sB 128x64 = 48 KB live), swizzle
//            g' = g ^ (r&7) within 8-granule rows (conflict-free, same
//            bank math as the verified 16-granule scheme).
//   GEMM1  : verified 64x64 wave tile, grid 4x2, 16x16x32, acc[4][4].
//   transp : acc -> sZ[pair][k'=d*32+c] (64 KB overlay), pair = iL*4+jL.
//   GEMM2  : 32x32x16, wave = (og = w&3: 32 o, kh = w>>2: K half).
//            M=32 = ALL pairs; wf per block = wo3 exactly once (256 KB).
//   reduce : fpart stride 132 (pad 4) -> conflict-free writes AND epilogue
//            reads (fixes R2's stride-8 bank-quad bug). 2 partials/thread,
//            coalesced float4 stores.
// ---------------------------------------------------------------------------
__global__ __launch_bounds__(512, 4) void fused_kernel(
    const unsigned short* __restrict__ a_t, const unsigned short* __restrict__ b_t,
    const unsigned short* __restrict__ wo3, const float* __restrict__ rnm,
    const float* __restrict__ bo, float* __restrict__ out) {
  extern __shared__ __align__(16) unsigned short smem[];
  unsigned short* sA = smem;            // 256 x 64 ushort = 32 KB
  unsigned short* sB = smem + 16384;    // 128 x 64 ushort = 16 KB
  unsigned short* sZ = smem;            // 32 pairs x 1024 ushort = 64 KB overlay
  float* fpart = (float*)smem;          // 2 x 32 x 132 f32 = 33 KB overlay

  const int t = threadIdx.x, w = t >> 6, l = t & 63;
  const int lq = l >> 4, lr = l & 15;
  const int bx = blockIdx.x, by = blockIdx.y;

  const unsigned short* srcA = a_t + (size_t)bx * 32768;   // 8 i x 32 c x 128 s
  const unsigned short* srcB = b_t + (size_t)by * 16384;   // 4 j x 32 d x 128 s

  // GEMM1: wave (wy, wx) owns 64x64 of the 256x128 product
  const int wy = (w >> 1) * 64, wx = (w & 1) * 64;
  f32x4 acc[4][4];
  #pragma unroll
  for (int a = 0; a < 4; a++)
    #pragma unroll
    for (int c = 0; c < 4; c++) acc[a][c] = (f32x4){0.f, 0.f, 0.f, 0.f};

  // ---- K-chunked stage + GEMM1 (chunk h covers k in [h*64, h*64+64)) ----
  #pragma unroll 1
  for (int h = 0; h < 2; h++) {
    if (h) __syncthreads();            // chunk-0 fragment reads done
    #pragma unroll
    for (int it = 0; it < 4; it++) {   // A: 2048 granules
      const int idx = it * 512 + t;
      const int r = idx >> 3, g = idx & 7;
      const bf16x8 v = *(const bf16x8*)(srcA + r * 128 + h * 64 + g * 8);
      *(bf16x8*)(&sA[r * 64 + ((g ^ (r & 7)) << 3)]) = v;
    }
    #pragma unroll
    for (int it = 0; it < 2; it++) {   // B: 1024 granules
      const int idx = it * 512 + t;
      const int r = idx >> 3, g = idx & 7;
      const bf16x8 v = *(const bf16x8*)(srcB + r * 128 + h * 64 + g * 8);
      *(bf16x8*)(&sB[r * 64 + ((g ^ (r & 7)) << 3)]) = v;
    }
    __syncthreads();

    #pragma unroll
    for (int ks2 = 0; ks2 < 2; ks2++) {
      const int gi = ks2 * 4 + lq;     // granule within chunk
      bf16x8 afr[4], bfr[4];
      #pragma unroll
      for (int a = 0; a < 4; a++) {
        const int ra = wy + a * 16 + lr;
        afr[a] = *(const bf16x8*)(&sA[ra * 64 + ((gi ^ (ra & 7)) << 3)]);
        const int rb = wx + a * 16 + lr;
        bfr[a] = *(const bf16x8*)(&sB[rb * 64 + ((gi ^ (rb & 7)) << 3)]);
      }
      #pragma unroll
      for (int a = 0; a < 4; a++)
        #pragma unroll
        for (int c = 0; c < 4; c++)
          acc[a][c] = __builtin_amdgcn_mfma_f32_16x16x32_bf16(afr[a], bfr[c], acc[a][c], 0, 0, 0);
    }
  }
  __syncthreads();  // all GEMM1 reads done before sZ overlays sA/sB

  // ---- transpose: acc (C/D layout) -> sZ[pair][k'=d*32+c] ----
  // pair = (zrb>>5)*4 + (zc>>5); granule map gp = (g&~7)|((g^(g>>3)^pair)&7)
  #pragma unroll
  for (int a = 0; a < 4; a++) {
    #pragma unroll
    for (int c = 0; c < 4; c++) {
      const int zrb = wy + a * 16 + lq * 4;
      const int zc  = wx + c * 16 + lr;
      const int pr = (zrb >> 5) * 4 + (zc >> 5);      // 0..31
      const int off = (zc & 31) * 32 + (zrb & 31);
      const int g = off >> 3;
      const int gp = (g & ~7) | ((g ^ (g >> 3) ^ pr) & 7);
      uint2 q;
      q.x = pk2(acc[a][c][0], acc[a][c][1]);
      q.y = pk2(acc[a][c][2], acc[a][c][3]);
      *(uint2*)(&sZ[pr * 1024 + gp * 8 + (off & 7)]) = q;
    }
  }
  __syncthreads();

  // ---- GEMM2: 32x32x16, M = 32 pairs, wave = (og, kh) ----
  const int og = w & 3, kh = w >> 2;
  const int pA = l & 31;
  const unsigned short* wop =
      wo3 + ((size_t)(og * 64 + kh * 32) * 64 + l) * 8;
  f32x16 acc2;
  #pragma unroll
  for (int r = 0; r < 16; r++) acc2[r] = 0.f;

  #pragma unroll 8
  for (int j = 0; j < 32; j++) {
    const int s = kh * 32 + j;                 // global k-step (16 k each)
    const int g = s * 2 + (l >> 5);            // granule of this lane's chunk
    const int gA = (g & ~7) | ((g ^ (g >> 3) ^ pA) & 7);
    const bf16x8 zf = *(const bf16x8*)(&sZ[pA * 1024 + gA * 8]);
    const bf16x8 wf = *(const bf16x8*)(wop + (size_t)j * 512);
    acc2 = __builtin_amdgcn_mfma_f32_32x32x16_bf16(zf, wf, acc2, 0, 0, 0);
  }
  __syncthreads();   // all z reads done; sZ region now free for partials

  // ---- kh-partials -> fpart (stride 132: pad -> conflict-free) ----
  const int oc = og * 32 + (l & 31);
  #pragma unroll
  for (int r = 0; r < 16; r++) {
    const int row = (r & 3) + 8 * (r >> 2) + 4 * (l >> 5);   // pair 0..31
    fpart[kh * 4224 + row * 132 + oc] = acc2[r];
  }
  __syncthreads();

  // ---- epilogue: thread -> (pair = t>>4, 8 consecutive o) ----
  const int pair = t >> 4;              // 0..31
  const int ob   = (t & 15) * 8;        // 0..120
  const float4 bo0 = *(const float4*)(bo + ob);
  const float4 bo1 = *(const float4*)(bo + ob + 4);

  const int ii = bx * 8 + (pair >> 2), jj = by * 4 + (pair & 3);
  const float sc = rnm[ii * N_DIM + jj];

  const int fb = pair * 132 + ob;
  f32x4 u0 = {0.f, 0.f, 0.f, 0.f}, u1 = {0.f, 0.f, 0.f, 0.f};
  #pragma unroll
  for (int q = 0; q < 2; q++) {
    u0 += *(const f32x4*)(&fpart[q * 4224 + fb]);
    u1 += *(const f32x4*)(&fpart[q * 4224 + fb + 4]);
  }
  float* po = out + ((size_t)(ii * N_DIM + jj)) * COUT + ob;
  float4 w0, w1;
  w0.x = u0[0] * sc + bo0.x; w0.y = u0[1] * sc + bo0.y;
  w0.z = u0[2] * sc + bo0.z; w0.w = u0[3] * sc + bo0.w;
  w1.x = u1[0] * sc + bo1.x; w1.y = u1[1] * sc + bo1.y;
  w1.z = u1[2] * sc + bo1.z; w1.w = u1[3] * sc + bo1.w;
  *(float4*)(po)     = w0;
  *(float4*)(po + 4) = w1;
}

// ---------------------------------------------------------------------------
extern "C" void kernel_launch(void* const* d_in, const int* in_sizes, int n_in,
                              void* d_out, int out_size, void* d_ws, size_t ws_size,
                              hipStream_t stream) {
  const float* m     = (const float*)d_in[0];
  const float* mask  = (const float*)d_in[1];
  const float* gamma = (const float*)d_in[2];
  const float* beta  = (const float*)d_in[3];
  const float* Wa    = (const float*)d_in[4];
  const float* Wb    = (const float*)d_in[5];
  const float* Wo    = (const float*)d_in[6];
  const float* bo    = (const float*)d_in[7];
  float* out = (float*)d_out;

  char* ws = (char*)d_ws;
  float*          rnm = (float*)(ws);                     // 256 KB
  unsigned short* wo3 = (unsigned short*)(ws + 262144);   // 256 KB
  unsigned short* a_t = (unsigned short*)(ws + 524288);   //   2 MB
  unsigned short* b_t = (unsigned short*)(ws + 2621440);  //   2 MB

  hipFuncSetAttribute((const void*)fused_kernel,
                      hipFuncAttributeMaxDynamicSharedMemorySize, 65536);

  lnp_prep_kernel<<<1408, 256, 0, stream>>>(m, mask, gamma, beta, Wa, Wb, Wo,
                                            rnm, wo3, a_t, b_t);
  fused_kernel<<<dim3(32, 64), 512, 65536, stream>>>(a_t, b_t, wo3, rnm, bo, out);
}

// Round 4
// 144.650 us; speedup vs baseline: 1.5179x; 1.0164x over previous
//
#include <hip/hip_runtime.h>
#include <hip/hip_bf16.h>

#define S_DIM 128
#define N_DIM 256
#define CIN   256
#define CH    32
#define COUT  128

typedef __attribute__((ext_vector_type(8))) short bf16x8;
typedef __attribute__((ext_vector_type(4))) float f32x4;
typedef __attribute__((ext_vector_type(16))) float f32x16;

__device__ __forceinline__ unsigned short f2bf(float f) {
  union { float f; unsigned int u; } v; v.f = f;
  unsigned int u = v.u;
  return (unsigned short)((u + 0x7FFFu + ((u >> 16) & 1u)) >> 16);
}

// packed f32x2 -> bf16x2 (RNE)
__device__ __forceinline__ unsigned int pk2(float x, float y) {
  float2 f2; f2.x = x; f2.y = y;
  __hip_bfloat162 h = __float22bfloat162_rn(f2);
  union { __hip_bfloat162 h; unsigned int u; } c; c.h = h;
  return c.u;
}

// ---------------------------------------------------------------------------
// Front-end (R4-verified, unchanged): merged LN+projection and prep.
//   blocks 0..1023   : LayerNorm + MFMA projection (wab in LDS)
//   blocks 1024..1151: wo3 = Wo bf16 packed for 32x32x16 B-frags
//   blocks 1152..1407: rnm = 1 / clip(mask^T mask, 1)
// ---------------------------------------------------------------------------
__global__ __launch_bounds__(256) void lnp_prep_kernel(
    const float* __restrict__ m, const float* __restrict__ mask,
    const float* __restrict__ gamma, const float* __restrict__ beta,
    const float* __restrict__ Wa, const float* __restrict__ Wb,
    const float* __restrict__ Wo,
    float* __restrict__ rnm, unsigned short* __restrict__ wo3,
    unsigned short* __restrict__ a_t, unsigned short* __restrict__ b_t) {
  const int b = blockIdx.x, t = threadIdx.x;
  if (b < 1024) {
    __shared__ __align__(16) unsigned short mn[32][264];   // +8 pad
    __shared__ __align__(16) unsigned short wabs[64 * 256];
    const int i = b & 255, s0 = (b >> 8) * 32;
    const int w = t >> 6, l = t & 63, lq = l >> 4, lr = l & 15;

    // Wa/Wb -> wabs, granule-swizzled: g' = (g&16)|((g ^ (r&15))&15)
    #pragma unroll
    for (int it = 0; it < 8; it++) {
      const int gi = it * 256 + t;       // granule 0..2047 (64 rows x 32)
      const int r = gi >> 5, g = gi & 31;
      const float* src = (r < 32) ? (Wa + r * 256 + g * 8)
                                  : (Wb + (r - 32) * 256 + g * 8);
      const int gp = (g & 16) | ((g ^ (r & 15)) & 15);
      unsigned short* dst = &wabs[r * 256 + gp * 8];
      const float4 v0 = *(const float4*)(src);
      const float4 v1 = *(const float4*)(src + 4);
      dst[0] = f2bf(v0.x); dst[1] = f2bf(v0.y); dst[2] = f2bf(v0.z); dst[3] = f2bf(v0.w);
      dst[4] = f2bf(v1.x); dst[5] = f2bf(v1.y); dst[6] = f2bf(v1.z); dst[7] = f2bf(v1.w);
    }

    const float4 g4 = *(const float4*)(gamma + l * 4);
    const float4 b4 = *(const float4*)(beta + l * 4);

    for (int rr = 0; rr < 8; rr++) {
      const int r = w * 8 + rr;
      const int s = s0 + r;
      const float4 v = *(const float4*)(m + ((size_t)(s * N_DIM + i)) * CIN + l * 4);
      float sum = v.x + v.y + v.z + v.w;
      float sq  = v.x * v.x + v.y * v.y + v.z * v.z + v.w * v.w;
      #pragma unroll
      for (int off = 32; off > 0; off >>= 1) {
        sum += __shfl_down(sum, off);
        sq  += __shfl_down(sq, off);
      }
      sum = __shfl(sum, 0); sq = __shfl(sq, 0);
      const float mu = sum * (1.0f / CIN);
      const float var = fmaxf(sq * (1.0f / CIN) - mu * mu, 0.0f);
      const float rs = rsqrtf(var + 1e-5f);
      const float mk = mask[s * N_DIM + i];
      ushort4 p;
      p.x = f2bf(((v.x - mu) * rs * g4.x + b4.x) * mk);
      p.y = f2bf(((v.y - mu) * rs * g4.y + b4.y) * mk);
      p.z = f2bf(((v.z - mu) * rs * g4.z + b4.z) * mk);
      p.w = f2bf(((v.w - mu) * rs * g4.w + b4.w) * mk);
      *(ushort4*)(&mn[r][l * 4]) = p;
    }
    __syncthreads();

    // MFMA: M=32 s-rows, N=64 [Wa|Wb], K=256
    const int wm = w & 1;
    const int n2 = w >> 1;
    f32x4 acc0 = {0.f, 0.f, 0.f, 0.f}, acc1 = {0.f, 0.f, 0.f, 0.f};
    #pragma unroll
    for (int ks = 0; ks < 8; ks++) {
      const int k0 = ks * 32 + lq * 8;
      const int g = ks * 4 + lq;
      const int gp = (g & 16) | ((g ^ lr) & 15);
      const bf16x8 af = *(const bf16x8*)(&mn[wm * 16 + lr][k0]);
      const bf16x8 bf0 = *(const bf16x8*)(&wabs[(n2 * 32 + lr) * 256 + gp * 8]);
      const bf16x8 bf1 = *(const bf16x8*)(&wabs[(n2 * 32 + 16 + lr) * 256 + gp * 8]);
      acc0 = __builtin_amdgcn_mfma_f32_16x16x32_bf16(af, bf0, acc0, 0, 0, 0);
      acc1 = __builtin_amdgcn_mfma_f32_16x16x32_bf16(af, bf1, acc1, 0, 0, 0);
    }

    unsigned short* dst = (n2 == 0) ? a_t : b_t;
    const int scol = s0 + wm * 16 + lq * 4;
    ushort4 q0, q1;
    q0.x = f2bf(acc0[0]); q0.y = f2bf(acc0[1]); q0.z = f2bf(acc0[2]); q0.w = f2bf(acc0[3]);
    q1.x = f2bf(acc1[0]); q1.y = f2bf(acc1[1]); q1.z = f2bf(acc1[2]); q1.w = f2bf(acc1[3]);
    *(ushort4*)(dst + ((size_t)(i * CH + lr)) * S_DIM + scol) = q0;
    *(ushort4*)(dst + ((size_t)(i * CH + 16 + lr)) * S_DIM + scol) = q1;
  } else if (b < 1152) {
    const int r = b - 1024;  // 0..127
    #pragma unroll
    for (int q = 0; q < 4; q++) {
      const int f = r * 1024 + q * 256 + t;        // 0..131071
      const int e = f & 7, l = (f >> 3) & 63;
      const int step = (f >> 9) & 63, og = f >> 15;
      const int kp = step * 16 + (l >> 5) * 8 + e;
      const int c = kp & 31, d = kp >> 5;
      const int o = og * 32 + (l & 31);
      wo3[f] = f2bf(Wo[o * 1024 + c * 32 + d]);
    }
  } else {
    const int i = b - 1152;  // 0..255
    float acc = 0.f;
    #pragma unroll 8
    for (int s = 0; s < S_DIM; s++)
      acc += mask[s * N_DIM + i] * mask[s * N_DIM + t];
    acc = fmaxf(acc, 1.0f);
    rnm[i * N_DIM + t] = 1.0f / acc;
  }
}

// ---------------------------------------------------------------------------
// fused v9: v8 structure + wf (wo3) register prefetch pipeline (T14).
// R3 showed 2-block residency alone gives zero: co-resident blocks convoy
// through the same phases, and GEMM2's wf L2 stream (512 KB/round, ~9.1K cyc
// on the VM pipe) is the largest serialized term. Fix: double-buffered
// batch-of-4 wf register prefetch — batch 0 issued before the transpose
// phase (VM works under VALU/LDS), then 2-batches-ahead inside the GEMM2
// loop. rnm/bo epilogue loads hoisted ahead of GEMM2. All array indices
// compile-time (full unroll) to avoid scratch.
// ---------------------------------------------------------------------------
__global__ __launch_bounds__(512, 4) void fused_kernel(
    const unsigned short* __restrict__ a_t, const unsigned short* __restrict__ b_t,
    const unsigned short* __restrict__ wo3, const float* __restrict__ rnm,
    const float* __restrict__ bo, float* __restrict__ out) {
  extern __shared__ __align__(16) unsigned short smem[];
  unsigned short* sA = smem;            // 256 x 64 ushort = 32 KB
  unsigned short* sB = smem + 16384;    // 128 x 64 ushort = 16 KB
  unsigned short* sZ = smem;            // 32 pairs x 1024 ushort = 64 KB overlay
  float* fpart = (float*)smem;          // 2 x 32 x 132 f32 = 33 KB overlay

  const int t = threadIdx.x, w = t >> 6, l = t & 63;
  const int lq = l >> 4, lr = l & 15;
  const int bx = blockIdx.x, by = blockIdx.y;

  const unsigned short* srcA = a_t + (size_t)bx * 32768;   // 8 i x 32 c x 128 s
  const unsigned short* srcB = b_t + (size_t)by * 16384;   // 4 j x 32 d x 128 s

  // GEMM2 wave job (needed early for the wf prefetch)
  const int og = w & 3, kh = w >> 2;
  const int pA = l & 31;
  const unsigned short* wop =
      wo3 + ((size_t)(og * 64 + kh * 32) * 64 + l) * 8;

  // GEMM1: wave (wy, wx) owns 64x64 of the 256x128 product
  const int wy = (w >> 1) * 64, wx = (w & 1) * 64;
  f32x4 acc[4][4];
  #pragma unroll
  for (int a = 0; a < 4; a++)
    #pragma unroll
    for (int c = 0; c < 4; c++) acc[a][c] = (f32x4){0.f, 0.f, 0.f, 0.f};

  // ---- K-chunked stage + GEMM1 (chunk h covers k in [h*64, h*64+64)) ----
  #pragma unroll 1
  for (int h = 0; h < 2; h++) {
    if (h) __syncthreads();            // chunk-0 fragment reads done
    #pragma unroll
    for (int it = 0; it < 4; it++) {   // A: 2048 granules
      const int idx = it * 512 + t;
      const int r = idx >> 3, g = idx & 7;
      const bf16x8 v = *(const bf16x8*)(srcA + r * 128 + h * 64 + g * 8);
      *(bf16x8*)(&sA[r * 64 + ((g ^ (r & 7)) << 3)]) = v;
    }
    #pragma unroll
    for (int it = 0; it < 2; it++) {   // B: 1024 granules
      const int idx = it * 512 + t;
      const int r = idx >> 3, g = idx & 7;
      const bf16x8 v = *(const bf16x8*)(srcB + r * 128 + h * 64 + g * 8);
      *(bf16x8*)(&sB[r * 64 + ((g ^ (r & 7)) << 3)]) = v;
    }
    __syncthreads();

    #pragma unroll
    for (int ks2 = 0; ks2 < 2; ks2++) {
      const int gi = ks2 * 4 + lq;     // granule within chunk
      bf16x8 afr[4], bfr[4];
      #pragma unroll
      for (int a = 0; a < 4; a++) {
        const int ra = wy + a * 16 + lr;
        afr[a] = *(const bf16x8*)(&sA[ra * 64 + ((gi ^ (ra & 7)) << 3)]);
        const int rb = wx + a * 16 + lr;
        bfr[a] = *(const bf16x8*)(&sB[rb * 64 + ((gi ^ (rb & 7)) << 3)]);
      }
      #pragma unroll
      for (int a = 0; a < 4; a++)
        #pragma unroll
        for (int c = 0; c < 4; c++)
          acc[a][c] = __builtin_amdgcn_mfma_f32_16x16x32_bf16(afr[a], bfr[c], acc[a][c], 0, 0, 0);
    }
  }

  // wf batch 0 prefetch: issued before the transpose phase so the VM pipe
  // overlaps the VALU/LDS transpose work (loads can't sink past barriers).
  bf16x8 wfb0[4], wfb1[4];
  #pragma unroll
  for (int q = 0; q < 4; q++)
    wfb0[q] = *(const bf16x8*)(wop + (size_t)q * 512);

  __syncthreads();  // all GEMM1 reads done before sZ overlays sA/sB

  // ---- transpose: acc (C/D layout) -> sZ[pair][k'=d*32+c] ----
  // pair = (zrb>>5)*4 + (zc>>5); granule map gp = (g&~7)|((g^(g>>3)^pair)&7)
  #pragma unroll
  for (int a = 0; a < 4; a++) {
    #pragma unroll
    for (int c = 0; c < 4; c++) {
      const int zrb = wy + a * 16 + lq * 4;
      const int zc  = wx + c * 16 + lr;
      const int pr = (zrb >> 5) * 4 + (zc >> 5);      // 0..31
      const int off = (zc & 31) * 32 + (zrb & 31);
      const int g = off >> 3;
      const int gp = (g & ~7) | ((g ^ (g >> 3) ^ pr) & 7);
      uint2 q;
      q.x = pk2(acc[a][c][0], acc[a][c][1]);
      q.y = pk2(acc[a][c][2], acc[a][c][3]);
      *(uint2*)(&sZ[pr * 1024 + gp * 8 + (off & 7)]) = q;
    }
  }
  __syncthreads();

  // wf batch 1 + epilogue operands (rnm/bo) — all independent of GEMM2
  #pragma unroll
  for (int q = 0; q < 4; q++)
    wfb1[q] = *(const bf16x8*)(wop + (size_t)(4 + q) * 512);

  const int pair = t >> 4;              // 0..31
  const int ob   = (t & 15) * 8;        // 0..120
  const int ii = bx * 8 + (pair >> 2), jj = by * 4 + (pair & 3);
  const float sc = rnm[ii * N_DIM + jj];
  const float4 bo0 = *(const float4*)(bo + ob);
  const float4 bo1 = *(const float4*)(bo + ob + 4);

  // ---- GEMM2: 32x32x16, M = 32 pairs; wf from regs, 2 batches in flight ----
  f32x16 acc2;
  #pragma unroll
  for (int r = 0; r < 16; r++) acc2[r] = 0.f;

  #pragma unroll
  for (int jb = 0; jb < 8; jb++) {
    #pragma unroll
    for (int q = 0; q < 4; q++) {
      const int j = jb * 4 + q;
      const int s = kh * 32 + j;                 // global k-step (16 k each)
      const int g = s * 2 + (l >> 5);            // granule of this lane's chunk
      const int gA = (g & ~7) | ((g ^ (g >> 3) ^ pA) & 7);
      const bf16x8 zf = *(const bf16x8*)(&sZ[pA * 1024 + gA * 8]);
      const bf16x8 wf = (jb & 1) ? wfb1[q] : wfb0[q];
      acc2 = __builtin_amdgcn_mfma_f32_32x32x16_bf16(zf, wf, acc2, 0, 0, 0);
    }
    if (jb < 6) {
      #pragma unroll
      for (int q = 0; q < 4; q++) {
        const bf16x8 v = *(const bf16x8*)(wop + (size_t)((jb + 2) * 4 + q) * 512);
        if (jb & 1) wfb1[q] = v; else wfb0[q] = v;
      }
    }
  }
  __syncthreads();   // all z reads done; sZ region now free for partials

  // ---- kh-partials -> fpart (stride 132: pad -> conflict-free) ----
  const int oc = og * 32 + (l & 31);
  #pragma unroll
  for (int r = 0; r < 16; r++) {
    const int row = (r & 3) + 8 * (r >> 2) + 4 * (l >> 5);   // pair 0..31
    fpart[kh * 4224 + row * 132 + oc] = acc2[r];
  }
  __syncthreads();

  // ---- epilogue: thread -> (pair = t>>4, 8 consecutive o) ----
  const int fb = pair * 132 + ob;
  f32x4 u0 = {0.f, 0.f, 0.f, 0.f}, u1 = {0.f, 0.f, 0.f, 0.f};
  #pragma unroll
  for (int q = 0; q < 2; q++) {
    u0 += *(const f32x4*)(&fpart[q * 4224 + fb]);
    u1 += *(const f32x4*)(&fpart[q * 4224 + fb + 4]);
  }
  float* po = out + ((size_t)(ii * N_DIM + jj)) * COUT + ob;
  float4 w0, w1;
  w0.x = u0[0] * sc + bo0.x; w0.y = u0[1] * sc + bo0.y;
  w0.z = u0[2] * sc + bo0.z; w0.w = u0[3] * sc + bo0.w;
  w1.x = u1[0] * sc + bo1.x; w1.y = u1[1] * sc + bo1.y;
  w1.z = u1[2] * sc + bo1.z; w1.w = u1[3] * sc + bo1.w;
  *(float4*)(po)     = w0;
  *(float4*)(po + 4) = w1;
}

// ---------------------------------------------------------------------------
extern "C" void kernel_launch(void* const* d_in, const int* in_sizes, int n_in,
                              void* d_out, int out_size, void* d_ws, size_t ws_size,
                              hipStream_t stream) {
  const float* m     = (const float*)d_in[0];
  const float* mask  = (const float*)d_in[1];
  const float* gamma = (const float*)d_in[2];
  const float* beta  = (const float*)d_in[3];
  const float* Wa    = (const float*)d_in[4];
  const float* Wb    = (const float*)d_in[5];
  const float* Wo    = (const float*)d_in[6];
  const float* bo    = (const float*)d_in[7];
  float* out = (float*)d_out;

  char* ws = (char*)d_ws;
  float*          rnm = (float*)(ws);                     // 256 KB
  unsigned short* wo3 = (unsigned short*)(ws + 262144);   // 256 KB
  unsigned short* a_t = (unsigned short*)(ws + 524288);   //   2 MB
  unsigned short* b_t = (unsigned short*)(ws + 2621440);  //   2 MB

  hipFuncSetAttribute((const void*)fused_kernel,
                      hipFuncAttributeMaxDynamicSharedMemorySize, 65536);

  lnp_prep_kernel<<<1408, 256, 0, stream>>>(m, mask, gamma, beta, Wa, Wb, Wo,
                                            rnm, wo3, a_t, b_t);
  fused_kernel<<<dim3(32, 64), 512, 65536, stream>>>(a_t, b_t, wo3, rnm, bo, out);
}